// Round 12
// baseline (280.581 us; speedup 1.0000x reference)
//
#include <hip/hip_runtime.h>
#include <math.h>

#define D      256
#define K      16384
#define NPTS   8192
#define DELTA  0.2f
#define LCAP   4096
#define MAXCAP 4000000u

// d_out layout (all f32): zq[8,256,32,32] | indices[8192] | bit[8,32,32,256] | loss[1]
#define O_IDX  2097152
#define O_BIT  2105344
#define O_LOSS 4202496

typedef __attribute__((ext_vector_type(8))) short bf16x8;
typedef __attribute__((ext_vector_type(4))) float f32x4;
typedef unsigned long long u64;

__device__ __forceinline__ unsigned f2s(float f) {
    unsigned u = __float_as_uint(f);
    return (u & 0x80000000u) ? ~u : (u | 0x80000000u);
}
__device__ __forceinline__ float s2f(unsigned s) {
    return __uint_as_float((s & 0x80000000u) ? (s & 0x7fffffffu) : ~s);
}
__device__ __forceinline__ unsigned short f2bf(float f) {  // RNE
    unsigned u = __float_as_uint(f);
    u += 0x7fffu + ((u >> 16) & 1u);
    return (unsigned short)(u >> 16);
}

// k-major fragment layouts: X[(k>>3)][row][k&7], 16B per (row, k-chunk)
//   zfbT: [32][NPTS][8] bf16 ; ewbT: [32][K][8] bf16

// ---- merged prep: blocks [0,512) codebook; [512,640) z transpose; state init folded ----
__global__ __launch_bounds__(256) void prep(const float* __restrict__ E,
                                            const float* __restrict__ z,
                                            float* __restrict__ den,
                                            unsigned short* __restrict__ ewbT,
                                            unsigned short* __restrict__ zfbT,
                                            float* __restrict__ zf32,
                                            unsigned* __restrict__ gmax,
                                            u64* __restrict__ keys,
                                            unsigned* __restrict__ cnt) {
    const int blk = blockIdx.x, tid = threadIdx.x;
    if (blk < 512) {
        const int lane = tid & 63, wave = tid >> 6;
        if (blk < 32)        gmax[blk * 256 + tid] = 0u;
        else if (blk < 64)   keys[(blk - 32) * 256 + tid] = 0ull;
        else if (blk == 64 && tid < 2) cnt[tid] = 0u;
        #pragma unroll
        for (int j = 0; j < 8; ++j) {
            const int row = blk * 32 + wave * 8 + j;
            const float4 v = *(const float4*)(E + (size_t)row * D + lane * 4);
            float ss = v.x * v.x + v.y * v.y + v.z * v.z + v.w * v.w;
            #pragma unroll
            for (int o = 1; o < 64; o <<= 1) ss += __shfl_xor(ss, o);
            const float dn = fmaxf(sqrtf(ss), 1e-12f);
            const unsigned lo = (unsigned)f2bf(v.x / dn) | ((unsigned)f2bf(v.y / dn) << 16);
            const unsigned hi = (unsigned)f2bf(v.z / dn) | ((unsigned)f2bf(v.w / dn) << 16);
            *(uint2*)(ewbT + ((size_t)(lane >> 1) * K + row) * 8 + (lane & 1) * 4)
                = make_uint2(lo, hi);
            if (lane == 0) den[row] = dn;
        }
    } else {
        const int bi = blk - 512;
        const int b = bi >> 4, hw0 = (bi & 15) * 64;
        __shared__ float t[64][65];
        for (int dc = 0; dc < D; dc += 64) {
            #pragma unroll
            for (int it = 0; it < 16; ++it) {
                const int idx = it * 256 + tid;
                const int dl = idx >> 6, hw = idx & 63;
                t[dl][hw] = z[(size_t)(b * 256 + dc + dl) * 1024 + hw0 + hw];
            }
            __syncthreads();
            #pragma unroll
            for (int it = 0; it < 16; ++it) {
                const int idx = it * 256 + tid;
                const int pl = idx >> 6, dl = idx & 63;
                const float v = t[dl][pl];
                const int p = b * 1024 + hw0 + pl, k = dc + dl;
                zfbT[((size_t)(k >> 3) * NPTS + p) * 8 + (k & 7)] = f2bf(v);
                zf32[(size_t)p * D + k] = v;
            }
            __syncthreads();
        }
    }
}

// ================= A-stationary score body =================
// 8 waves; wave: m-strip (wave&3)*32, n-half (wave>>2)*64. A in 64 VGPRs (reused
// across subs); per sub all 32 B-fragments loaded up-front (deep ILP, no barriers).

#define SCORE_PROLOG()                                                              \
    const int tid = threadIdx.x, lane = tid & 63, wave = tid >> 6;                  \
    const int quad = lane >> 4, col = lane & 15;                                    \
    const int wm = wave & 3, wn = wave >> 2;                                        \
    const int m0 = blockIdx.x * 128;                                                \
    const int shsrc = lane & 48;                                                    \
    (void)shsrc;                                                                    \
    bf16x8 af[2][8];                                                                \
    {                                                                               \
        const unsigned short* pA = zfbT + ((size_t)quad * NPTS + m0 + wm * 32 + col) * 8; \
        _Pragma("unroll")                                                           \
        for (int mt = 0; mt < 2; ++mt)                                              \
            _Pragma("unroll")                                                       \
            for (int dc = 0; dc < 8; ++dc)                                          \
                af[mt][dc] = *(const bf16x8*)(pA + ((size_t)dc * 4 * NPTS + mt * 16) * 8); \
    }

#define SUB_GEMM(N0S)                                                               \
    f32x4 acc[2][4];                                                                \
    _Pragma("unroll")                                                               \
    for (int i = 0; i < 2; ++i)                                                     \
        _Pragma("unroll")                                                           \
        for (int j = 0; j < 4; ++j) acc[i][j] = (f32x4){0.f, 0.f, 0.f, 0.f};        \
    {                                                                               \
        const unsigned short* pB = ewbT + ((size_t)quad * K + (N0S) + wn * 64 + col) * 8; \
        bf16x8 bfr[8][4];                                                           \
        _Pragma("unroll")                                                           \
        for (int dc = 0; dc < 8; ++dc)                                              \
            _Pragma("unroll")                                                       \
            for (int nt = 0; nt < 4; ++nt)                                          \
                bfr[dc][nt] = *(const bf16x8*)(pB + ((size_t)dc * 4 * K + nt * 16) * 8); \
        _Pragma("unroll")                                                           \
        for (int dc = 0; dc < 8; ++dc)                                              \
            _Pragma("unroll")                                                       \
            for (int mt = 0; mt < 2; ++mt)                                          \
                _Pragma("unroll")                                                   \
                for (int nt = 0; nt < 4; ++nt)                                      \
                    acc[mt][nt] = __builtin_amdgcn_mfma_f32_16x16x32_bf16(af[mt][dc], bfr[dc][nt], \
                                                                          acc[mt][nt], 0, 0, 0); \
    }

#define APPEND_CANDS(N0S, THR2D)                                                    \
    _Pragma("unroll")                                                               \
    for (int mt = 0; mt < 2; ++mt) {                                                \
        _Pragma("unroll")                                                           \
        for (int r = 0; r < 4; ++r) {                                               \
            const float tp = THR2D[mt][r];                                          \
            const unsigned pt = m0 + wm * 32 + mt * 16 + quad * 4 + r;              \
            _Pragma("unroll")                                                       \
            for (int nt = 0; nt < 4; ++nt) {                                        \
                const float v = acc[mt][nt][r];                                     \
                if (v >= tp) {                                                      \
                    const unsigned slot = atomicAdd(&lcount, 1u);                   \
                    const unsigned code = (N0S) + wn * 64 + nt * 16 + col;          \
                    const u64 e = ((u64)((pt << 14) | code) << 32) | f2s(v);        \
                    if (slot < LCAP) lbuf[slot] = e;                                \
                    else {                                                          \
                        const unsigned g = atomicAdd(cnt, 1u);                      \
                        if (g < cap) cand[g] = e;                                   \
                    }                                                               \
                }                                                                   \
            }                                                                       \
        }                                                                           \
    }

#define FLUSH_LBUF()                                                                \
    const unsigned m_ = lcount < LCAP ? lcount : LCAP;                              \
    if (tid == 0) lbase = atomicAdd(cnt, m_);                                       \
    __syncthreads();                                                                \
    for (unsigned i = tid; i < m_; i += 512) {                                      \
        const unsigned g = lbase + i;                                               \
        if (g < cap) cand[g] = lbuf[i];                                             \
    }

// ---- phase 1: codes [0,1024). Self-seeded LDS running thresholds; publish gmax. ----
__global__ __launch_bounds__(512, 2) void score_seed(const unsigned short* __restrict__ zfbT,
                                                     const unsigned short* __restrict__ ewbT,
                                                     unsigned* __restrict__ gmax,
                                                     u64* __restrict__ cand,
                                                     unsigned* __restrict__ cnt,
                                                     unsigned cap) {
    __shared__ unsigned thrS[128];
    __shared__ u64 lbuf[LCAP];
    __shared__ unsigned lcount, lbase;

    SCORE_PROLOG()
    if (tid < 128) thrS[tid] = 0u;
    if (tid == 0) lcount = 0u;
    __syncthreads();

    for (int sub = 0; sub < 8; ++sub) {
        const int n0s = sub * 128;
        SUB_GEMM(n0s)

        // per-point max over this wave's 64 codes
        float red[2][4], thr[2][4];
        #pragma unroll
        for (int mt = 0; mt < 2; ++mt)
            #pragma unroll
            for (int r = 0; r < 4; ++r)
                red[mt][r] = fmaxf(fmaxf(acc[mt][0][r], acc[mt][1][r]),
                                   fmaxf(acc[mt][2][r], acc[mt][3][r]));
        #pragma unroll
        for (int off = 1; off < 16; off <<= 1)
            #pragma unroll
            for (int mt = 0; mt < 2; ++mt)
                #pragma unroll
                for (int r = 0; r < 4; ++r)
                    red[mt][r] = fmaxf(red[mt][r], __shfl_xor(red[mt][r], off));
        #pragma unroll
        for (int mt = 0; mt < 2; ++mt)
            #pragma unroll
            for (int r = 0; r < 4; ++r) {
                unsigned cur = 0;
                if (col == 0) {
                    const unsigned enc = f2s(red[mt][r]);
                    const unsigned old = atomicMax(&thrS[wm * 32 + mt * 16 + quad * 4 + r], enc);
                    cur = old > enc ? old : enc;
                }
                cur = (unsigned)__shfl((int)cur, shsrc);
                thr[mt][r] = s2f(cur) - DELTA;
            }
        APPEND_CANDS(n0s, thr)
    }

    __syncthreads();
    if (tid < 128) atomicMax(&gmax[m0 + tid], thrS[tid]);
    FLUSH_LBUF()
}

// ---- phase 2: codes [1024,16384). Static thresholds from gmax. ----
__global__ __launch_bounds__(512, 2) void score_main(const unsigned short* __restrict__ zfbT,
                                                     const unsigned short* __restrict__ ewbT,
                                                     const unsigned* __restrict__ gmax,
                                                     u64* __restrict__ cand,
                                                     unsigned* __restrict__ cnt,
                                                     unsigned cap) {
    __shared__ float thrL[128];
    __shared__ u64 lbuf[LCAP];
    __shared__ unsigned lcount, lbase;

    SCORE_PROLOG()
    const int nbase = 1024 + blockIdx.y * 1024;
    if (tid < 128) thrL[tid] = s2f(gmax[m0 + tid]) - DELTA;
    if (tid == 0) lcount = 0u;
    __syncthreads();

    float thr[2][4];
    #pragma unroll
    for (int mt = 0; mt < 2; ++mt)
        #pragma unroll
        for (int r = 0; r < 4; ++r)
            thr[mt][r] = thrL[wm * 32 + mt * 16 + quad * 4 + r];

    for (int sub = 0; sub < 8; ++sub) {
        const int n0s = nbase + sub * 128;
        SUB_GEMM(n0s)
        APPEND_CANDS(n0s, thr)
    }

    __syncthreads();
    FLUSH_LBUF()
}

// ---- final per-point bf16 max over candidates ----
__global__ __launch_bounds__(256) void cand_max(const u64* __restrict__ cand,
                                                const unsigned* __restrict__ cnt,
                                                unsigned* __restrict__ gmax,
                                                unsigned cap) {
    const unsigned total = min(cnt[0], cap);
    const unsigned stride = gridDim.x * 256;
    for (unsigned i = blockIdx.x * 256 + threadIdx.x; i < total; i += stride) {
        const u64 e = cand[i];
        atomicMax(&gmax[(unsigned)(e >> 46)], (unsigned)(e & 0xffffffffull));
    }
}

// ---- lane-parallel filter + ballot-compacted wave-cooperative fp32 rescore ----
__global__ __launch_bounds__(256) void rescore(const float* __restrict__ zf32,
                                               const float* __restrict__ E,
                                               const float* __restrict__ den,
                                               const unsigned* __restrict__ gmax,
                                               const u64* __restrict__ cand,
                                               const unsigned* __restrict__ cnt,
                                               u64* __restrict__ keys,
                                               unsigned cap) {
    const unsigned total = min(cnt[0], cap);
    const int lane = threadIdx.x & 63;
    const unsigned w = (blockIdx.x * 256 + threadIdx.x) >> 6;
    const unsigned nw = gridDim.x * 4;
    for (unsigned base = w * 64; base < total; base += nw * 64) {
        const unsigned i = base + lane;
        u64 e = 0;
        bool keep = false;
        if (i < total) {
            e = cand[i];
            const int p = (int)(e >> 46);
            keep = (s2f((unsigned)(e & 0xffffffffull)) >= s2f(gmax[p]) - DELTA);
        }
        u64 mask = __ballot(keep);
        while (mask) {
            const int src = __ffsll((long long)mask) - 1;
            mask &= mask - 1;
            const unsigned pc = (unsigned)__shfl((int)(unsigned)(e >> 32), src);
            const int p = pc >> 14, c = pc & 16383;
            const float dinv = 1.0f / den[c];
            const float4 a = *(const float4*)(zf32 + (size_t)p * D + lane * 4);
            const float4 b = *(const float4*)(E + (size_t)c * D + lane * 4);
            float sv = fmaf(a.x, b.x * dinv, fmaf(a.y, b.y * dinv,
                       fmaf(a.z, b.z * dinv, a.w * (b.w * dinv))));
            #pragma unroll
            for (int o = 1; o < 64; o <<= 1) sv += __shfl_xor(sv, o);
            if (lane == 0)
                atomicMax(keys + p, ((u64)f2s(sv) << 32) | (unsigned)(16383 - c));
        }
    }
}

// ---- gather + outputs (LDS transpose for coalesced zq writes) ----
__global__ __launch_bounds__(256) void finalize(const float* __restrict__ E,
                                                const float* __restrict__ den,
                                                const u64* __restrict__ keys,
                                                float* __restrict__ out) {
    __shared__ float t[32][257];
    __shared__ int sIdx[32];
    __shared__ float sDen[32];
    const int tid = threadIdx.x;
    const int n0 = blockIdx.x * 32;
    if (tid < 32) {
        const u64 key = keys[n0 + tid];
        const int idx = 16383 - (int)(unsigned)(key & 0xffffffffull);
        sIdx[tid] = idx;
        sDen[tid] = den[idx];
        out[O_IDX + n0 + tid] = (float)idx;
    }
    __syncthreads();
    const float S = 5.65685424949238019520675489683895f;  // sqrt(32)
    #pragma unroll 4
    for (int i = 0; i < 32; ++i) {
        const float v = E[(size_t)sIdx[i] * D + tid] / sDen[i];
        t[i][tid] = v;
        out[O_BIT + (size_t)(n0 + i) * D + tid] = (float)((int)(v * S) + 4);
    }
    __syncthreads();
    const int b = n0 >> 10, hw0 = n0 & 1023;
    const int hwl = tid & 31, cg = tid >> 5;
    #pragma unroll 4
    for (int cc = 0; cc < 32; ++cc) {
        const int c = cc * 8 + cg;
        out[(size_t)(b * 256 + c) * 1024 + hw0 + hwl] = t[hwl][c];
    }
    if (n0 == 0 && tid == 0) out[O_LOSS] = 0.0f;
}

extern "C" void kernel_launch(void* const* d_in, const int* in_sizes, int n_in,
                              void* d_out, int out_size, void* d_ws, size_t ws_size,
                              hipStream_t stream) {
    const float* z = (const float*)d_in[0];
    const float* E = (const float*)d_in[1];
    float* out = (float*)d_out;

    char* w = (char*)d_ws;
    unsigned short* ewbT = (unsigned short*)w;  w += (size_t)K * D * 2;      //  8 MB
    unsigned short* zfbT = (unsigned short*)w;  w += (size_t)NPTS * D * 2;   //  4 MB
    float*          zf32 = (float*)w;           w += (size_t)NPTS * D * 4;   //  8 MB
    u64*            keys = (u64*)w;             w += (size_t)NPTS * 8;       // 64 KB
    float*          den  = (float*)w;           w += (size_t)K * 4;          // 64 KB
    unsigned*       gmax = (unsigned*)w;        w += (size_t)NPTS * 4;       // 32 KB
    unsigned*       cnt  = (unsigned*)w;        w += 256;
    u64*            cand = (u64*)w;             // remainder of ws
    const size_t fixed = (size_t)(w - (char*)d_ws);
    const size_t avail = ws_size > fixed ? (ws_size - fixed) / 8 : 0;
    const unsigned cap = (unsigned)(avail < (size_t)MAXCAP ? avail : (size_t)MAXCAP);

    prep<<<640, 256, 0, stream>>>(E, z, den, ewbT, zfbT, zf32, gmax, keys, cnt);

    score_seed<<<64, 512, 0, stream>>>(zfbT, ewbT, gmax, cand, cnt, cap);
    dim3 gmain(64, 15);
    score_main<<<gmain, 512, 0, stream>>>(zfbT, ewbT, gmax, cand, cnt, cap);

    cand_max<<<256, 256, 0, stream>>>(cand, cnt, gmax, cap);
    rescore<<<1024, 256, 0, stream>>>(zf32, E, den, gmax, cand, cnt, keys, cap);
    finalize<<<NPTS / 32, 256, 0, stream>>>(E, den, keys, out);
}